// Round 1
// baseline (147.475 us; speedup 1.0000x reference)
//
#include <hip/hip_runtime.h>

// CRF forward logZ. Inputs: words i32 [2048][256], ThetaB f32 [64][128],
// WA f32 [64][64], E f32 [50002][128]. out: f32 [2048].
// ws: Bt table in bf16, [50002][64] = 6.4 MB.
//
// R6: (1) __launch_bounds__(...,1) on both kernels: waves_per_eu=1 lifts the
//     register-pressure target so the scheduler keeps the 6-deep emission
//     prefetch ring LIVE (R5 got VGPR_Count=68 < live set ~120 with no scratch
//     writes -> loads were sunk to use points -> full gather latency per step,
//     1114 cy/step measured vs ~165 busy).
//     (2) emis_mfma: 4 waves/block (256 thr), one 16-row tile per wave ->
//     4x resident waves, enough bytes in flight to approach HBM BW.

#define NROWS 50002
#define EOS_T 62
#define BOS_T 63
#define TLEN  256
#define LOG64 4.1588830833596715f

typedef __attribute__((ext_vector_type(4))) short bf16x4;
typedef __attribute__((ext_vector_type(8))) short bf16x8;
typedef __attribute__((ext_vector_type(4))) float f32x4;

// round-half-up f32->bf16 pair pack (2 add + 1 perm); lo in low 16 bits
static __device__ __forceinline__ unsigned pack_bf2(float lo, float hi) {
    unsigned a = __float_as_uint(lo) + 0x8000u;
    unsigned b = __float_as_uint(hi) + 0x8000u;
    return __builtin_amdgcn_perm(b, a, 0x07060302u);
}
static __device__ __forceinline__ bf16x8 pack8(float4 a, float4 b) {
    union { bf16x8 v; unsigned u[4]; } r;
    r.u[0] = pack_bf2(a.x, a.y); r.u[1] = pack_bf2(a.z, a.w);
    r.u[2] = pack_bf2(b.x, b.y); r.u[3] = pack_bf2(b.z, b.w);
    return r.v;
}
static __device__ __forceinline__ bf16x4 pack4(float f0, float f1, float f2, float f3) {
    union { bf16x4 v; unsigned u[2]; } r;
    r.u[0] = pack_bf2(f0, f1); r.u[1] = pack_bf2(f2, f3);
    return r.v;
}

// ---------------------------------------------------------------------------
// Kernel 1: Btb[w][k] = bf16(exp(ThetaB[k].E[w])); tags 62,63 -> 0.
// 256 threads = 4 waves, one 16-row word-tile per wave. A = ThetaB (constant
// per wave), B = E rows loaded in native fragment layout.
// ---------------------------------------------------------------------------
__global__ __launch_bounds__(256, 1) void emis_mfma(
    const float* __restrict__ ThetaB, const float* __restrict__ E,
    uint2* __restrict__ Btb)
{
    const int lane = threadIdx.x & 63;
    const int wv   = threadIdx.x >> 6;       // tile index 0..3
    const int l = lane & 15;
    const int q = lane >> 4;

    // A-frags: A[m=l -> tag mt*16+l][k = q*8+j+32kc] = ThetaB[tag][k]
    bf16x8 Af[4][4];
#pragma unroll
    for (int mt = 0; mt < 4; ++mt)
#pragma unroll
        for (int kc = 0; kc < 4; ++kc) {
            const float4* tp = (const float4*)ThetaB + (mt * 16 + l) * 32 + kc * 8 + q * 2;
            Af[mt][kc] = pack8(tp[0], tp[1]);
        }

    const int row  = blockIdx.x * 64 + wv * 16 + l;
    const int rowc = row < NROWS ? row : NROWS - 1;
    // B-frags: B[k = q*8+j+32kc][n = l] = E[row][k]
    const float4* ep = (const float4*)E + (size_t)rowc * 32 + q * 2;
    bf16x8 Bf[4];
#pragma unroll
    for (int kc = 0; kc < 4; ++kc)
        Bf[kc] = pack8(ep[kc * 8], ep[kc * 8 + 1]);

    f32x4 D[4];
#pragma unroll
    for (int mt = 0; mt < 4; ++mt) { f32x4 z = {0.f, 0.f, 0.f, 0.f}; D[mt] = z; }
#pragma unroll
    for (int kc = 0; kc < 4; ++kc)
#pragma unroll
        for (int mt = 0; mt < 4; ++mt)
            D[mt] = __builtin_amdgcn_mfma_f32_16x16x32_bf16(Af[mt][kc], Bf[kc], D[mt], 0, 0, 0);

    if (row < NROWS) {
#pragma unroll
        for (int mt = 0; mt < 4; ++mt) {
            float v0 = expf(D[mt][0]), v1 = expf(D[mt][1]);
            float v2 = expf(D[mt][2]), v3 = expf(D[mt][3]);
            if (mt == 3 && q == 3) { v2 = 0.f; v3 = 0.f; }   // tags 62, 63
            uint2 o; o.x = pack_bf2(v0, v1); o.y = pack_bf2(v2, v3);
            Btb[(size_t)row * 16 + mt * 4 + q] = o;          // [w][tag] bf16
        }
    }
}

// ---------------------------------------------------------------------------
// Kernel 2: fwd/bwd recurrence, fully in registers.
// State X = B-operand: X[tag = kc*16+q*4+j][sent = l], bf16x4 per kc.
// fwd (wv=0): A = S^T (mask on m), X' = (S^T X) o e_t, t = 2..127.
// bwd (wv=1): A = S   (mask on k), X' = e_t o (S X),  t = 253..128.
// D[mt] tag set == B-frag[kc=mt] K set -> register handoff, no LDS per step.
// Emission ring: 6 bf16 buffers; words fetched 12 steps ahead (all in-bounds).
// Join: z = (S^T alpha_127) . (e_128 o q_129) via one LDS tile + dot.
// ---------------------------------------------------------------------------
__global__ __launch_bounds__(128, 1) void crf_fwdbwd(
    const int* __restrict__ words, const float* __restrict__ WA,
    const uint2* __restrict__ Btb, float* __restrict__ out)
{
    __shared__ float ytile[16 * 68];
    const int lane  = threadIdx.x & 63;
    const int wv    = threadIdx.x >> 6;          // 0 = fwd, 1 = bwd
    const int l     = lane & 15;
    const int q     = lane >> 4;
    const int sbase = blockIdx.x * 16;

    // Transition A-frags. S[i][j] = exp(WA[i][j]) * (j != BOS)/64.
    bf16x4 Sf[4][4];
#pragma unroll
    for (int mt = 0; mt < 4; ++mt)
#pragma unroll
        for (int kc = 0; kc < 4; ++kc) {
            float t[4];
#pragma unroll
            for (int j = 0; j < 4; ++j) {
                const int mg = mt * 16 + l;          // m index
                const int kg = kc * 16 + q * 4 + j;  // k index
                const int ii = wv ? mg : kg;         // WA row
                const int jj = wv ? kg : mg;         // WA col (masked: S's j)
                t[j] = (jj == BOS_T) ? 0.f : expf(WA[ii * 64 + jj]) * 0.015625f;
            }
            Sf[mt][kc] = pack4(t[0], t[1], t[2], t[3]);
        }

    // Init vector in X-layout, tag jt = kc*16 + q*4 + e:
    // fwd: S[BOS][jt] (alpha_1 pre-emission); bwd: S[jt][EOS] (q_255).
    float g[4][4];
#pragma unroll
    for (int kc = 0; kc < 4; ++kc)
#pragma unroll
        for (int e = 0; e < 4; ++e) {
            const int jt = kc * 16 + q * 4 + e;
            g[kc][e] = wv ? expf(WA[jt * 64 + EOS_T]) * 0.015625f
                          : ((jt == BOS_T) ? 0.f : expf(WA[BOS_T * 64 + jt]) * 0.015625f);
        }

    const int wb   = (sbase + l) * TLEN;
    const int tdir = wv ? -1 : 1;
    const int t0   = wv ? 254 : 1;

    auto eload = [&](int w, uint2 (&buf)[4]) {
#pragma unroll
        for (int kc = 0; kc < 4; ++kc)
            buf[kc] = Btb[(size_t)w * 16 + kc * 4 + q];
    };

    uint2 ei[4], ebA[4], ebB[4], ebC[4], ebD[4], ebE[4], ebF[4];
    eload(words[wb + t0], ei);
    eload(words[wb + t0 + 1 * tdir], ebA);   // emis for step 0
    eload(words[wb + t0 + 2 * tdir], ebB);
    eload(words[wb + t0 + 3 * tdir], ebC);
    eload(words[wb + t0 + 4 * tdir], ebD);
    eload(words[wb + t0 + 5 * tdir], ebE);
    eload(words[wb + t0 + 6 * tdir], ebF);   // emis for step 5
    int wdA = words[wb + t0 + 7 * tdir];     // word for step 6
    int wdB = words[wb + t0 + 8 * tdir];
    int wdC = words[wb + t0 + 9 * tdir];
    int wdD = words[wb + t0 + 10 * tdir];
    int wdE = words[wb + t0 + 11 * tdir];
    int wdF = words[wb + t0 + 12 * tdir];    // word for step 11

    // X init = g o e_{t0}
    bf16x4 X[4];
#pragma unroll
    for (int kc = 0; kc < 4; ++kc) {
        float f0 = __uint_as_float(ei[kc].x << 16)         * g[kc][0];
        float f1 = __uint_as_float(ei[kc].x & 0xffff0000u) * g[kc][1];
        float f2 = __uint_as_float(ei[kc].y << 16)         * g[kc][2];
        float f3 = __uint_as_float(ei[kc].y & 0xffff0000u) * g[kc][3];
        X[kc] = pack4(f0, f1, f2, f3);
    }

    float xf[4][4];                          // last step's f32 products (join)

    // substep consuming step i: refills eb for step i+6, fetches word i+12
    auto substep = [&](uint2 (&eb)[4], int& wd, int widx) {
        f32x4 D[4];
#pragma unroll
        for (int mt = 0; mt < 4; ++mt) { f32x4 z = {0.f, 0.f, 0.f, 0.f}; D[mt] = z; }
#pragma unroll
        for (int kc = 0; kc < 4; ++kc)
#pragma unroll
            for (int mt = 0; mt < 4; ++mt)
                D[mt] = __builtin_amdgcn_mfma_f32_16x16x16bf16_1k(Sf[mt][kc], X[kc], D[mt], 0, 0, 0);
#pragma unroll
        for (int kc = 0; kc < 4; ++kc) {
            float f0 = __uint_as_float(eb[kc].x << 16);
            float f1 = __uint_as_float(eb[kc].x & 0xffff0000u);
            float f2 = __uint_as_float(eb[kc].y << 16);
            float f3 = __uint_as_float(eb[kc].y & 0xffff0000u);
            xf[kc][0] = D[kc][0] * f0;  xf[kc][1] = D[kc][1] * f1;
            xf[kc][2] = D[kc][2] * f2;  xf[kc][3] = D[kc][3] * f3;
            X[kc] = pack4(xf[kc][0], xf[kc][1], xf[kc][2], xf[kc][3]);
        }
        eload(wd, eb);
        wd = words[wb + widx];
    };

    // 126 steps; word index bounds: fwd max t0+139=140<256, bwd min 254-138>=0
    for (int i = 0; i < 126; i += 6) {
        substep(ebA, wdA, t0 + tdir * (i + 13));
        substep(ebB, wdB, t0 + tdir * (i + 14));
        substep(ebC, wdC, t0 + tdir * (i + 15));
        substep(ebD, wdD, t0 + tdir * (i + 16));
        substep(ebE, wdE, t0 + tdir * (i + 17));
        substep(ebF, wdF, t0 + tdir * (i + 18));
    }

    if (wv == 0) {
        // extra step: Y = S^T alpha_127 (no emission) -> LDS
        f32x4 D[4];
#pragma unroll
        for (int mt = 0; mt < 4; ++mt) { f32x4 z = {0.f, 0.f, 0.f, 0.f}; D[mt] = z; }
#pragma unroll
        for (int kc = 0; kc < 4; ++kc)
#pragma unroll
            for (int mt = 0; mt < 4; ++mt)
                D[mt] = __builtin_amdgcn_mfma_f32_16x16x16bf16_1k(Sf[mt][kc], X[kc], D[mt], 0, 0, 0);
#pragma unroll
        for (int mt = 0; mt < 4; ++mt) {
            float4 o = {D[mt][0], D[mt][1], D[mt][2], D[mt][3]};
            *(float4*)&ytile[l * 68 + mt * 16 + q * 4] = o;
        }
    }
    __syncthreads();
    if (wv == 1) {
        // z[s] = sum_tag Y[tag][s] * X128[tag][s]
        float p = 0.f;
#pragma unroll
        for (int mt = 0; mt < 4; ++mt)
#pragma unroll
            for (int r = 0; r < 4; ++r)
                p = fmaf(ytile[l * 68 + mt * 16 + q * 4 + r], xf[mt][r], p);
        p += __shfl_xor(p, 16, 64);
        p += __shfl_xor(p, 32, 64);
        if (lane < 16)
            out[sbase + l] = logf(p) + 255.0f * LOG64;
    }
}

extern "C" void kernel_launch(void* const* d_in, const int* in_sizes, int n_in,
                              void* d_out, int out_size, void* d_ws, size_t ws_size,
                              hipStream_t stream) {
    const int*   words  = (const int*)d_in[0];
    const float* ThetaB = (const float*)d_in[1];
    const float* WA     = (const float*)d_in[2];
    const float* E      = (const float*)d_in[3];
    float*       outp   = (float*)d_out;
    uint2*       Btb    = (uint2*)d_ws;          // 50002*128 B = 6.4 MB

    // 782 blocks x 4 waves x 1 word-tile = 50048 >= 50002 rows
    emis_mfma<<<dim3(782), dim3(256), 0, stream>>>(ThetaB, E, Btb);
    // 128 blocks x (fwd wave + bwd wave), 16 sentences each
    crf_fwdbwd<<<dim3(128), dim3(128), 0, stream>>>(words, WA, Btb, outp);
}

// Round 2
// 129.676 us; speedup vs baseline: 1.1373x; 1.1373x over previous
//
#include <hip/hip_runtime.h>

// CRF forward logZ. Inputs: words i32 [2048][256], ThetaB f32 [64][128],
// WA f32 [64][64], E f32 [50002][128]. out: f32 [2048].
// ws: Bt table in bf16, [50002][64] = 6.4 MB.
//
// R7: (1) crf_fwdbwd: asm volatile memory clobber after each substep's
//     prefetch loads. R5/R6 showed VGPR_Count=68 (< live set ~120, no
//     spills): hipcc legally SANK the 6-deep emission ring's loads to
//     their use points (const __restrict__, no aliasing store), so every
//     step paid the full ~950cy gather latency serially (1114 cy/step
//     measured vs ~165 busy). The clobber makes the sink illegal; loads
//     stay >=6 steps ahead, waitcnts become counted.
//     (2) emis_mfma reverted to R5 form (1 wave/block, 4 tiles, Af
//     amortized) - the R6 4-wave split regressed ~7us.

#define NROWS 50002
#define EOS_T 62
#define BOS_T 63
#define TLEN  256
#define LOG64 4.1588830833596715f

typedef __attribute__((ext_vector_type(4))) short bf16x4;
typedef __attribute__((ext_vector_type(8))) short bf16x8;
typedef __attribute__((ext_vector_type(4))) float f32x4;

// round-half-up f32->bf16 pair pack (2 add + 1 perm); lo in low 16 bits
static __device__ __forceinline__ unsigned pack_bf2(float lo, float hi) {
    unsigned a = __float_as_uint(lo) + 0x8000u;
    unsigned b = __float_as_uint(hi) + 0x8000u;
    return __builtin_amdgcn_perm(b, a, 0x07060302u);
}
static __device__ __forceinline__ bf16x8 pack8(float4 a, float4 b) {
    union { bf16x8 v; unsigned u[4]; } r;
    r.u[0] = pack_bf2(a.x, a.y); r.u[1] = pack_bf2(a.z, a.w);
    r.u[2] = pack_bf2(b.x, b.y); r.u[3] = pack_bf2(b.z, b.w);
    return r.v;
}
static __device__ __forceinline__ bf16x4 pack4(float f0, float f1, float f2, float f3) {
    union { bf16x4 v; unsigned u[2]; } r;
    r.u[0] = pack_bf2(f0, f1); r.u[1] = pack_bf2(f2, f3);
    return r.v;
}

// ---------------------------------------------------------------------------
// Kernel 1: Btb[w][k] = bf16(exp(ThetaB[k].E[w])); tags 62,63 -> 0.
// MFMA GEMM, D[tag = mt*16+q*4+r][word = l]. A = ThetaB (constant per wave,
// amortized over 4 word-tiles), B = E rows loaded in native fragment layout.
// ---------------------------------------------------------------------------
__global__ __launch_bounds__(64) void emis_mfma(
    const float* __restrict__ ThetaB, const float* __restrict__ E,
    uint2* __restrict__ Btb)
{
    const int l = threadIdx.x & 15;
    const int q = threadIdx.x >> 4;

    // A-frags: A[m=l -> tag mt*16+l][k = q*8+j+32kc] = ThetaB[tag][k]
    bf16x8 Af[4][4];
#pragma unroll
    for (int mt = 0; mt < 4; ++mt)
#pragma unroll
        for (int kc = 0; kc < 4; ++kc) {
            const float4* tp = (const float4*)ThetaB + (mt * 16 + l) * 32 + kc * 8 + q * 2;
            Af[mt][kc] = pack8(tp[0], tp[1]);
        }

    const int base0 = blockIdx.x * 64;
#pragma unroll
    for (int it = 0; it < 4; ++it) {
        const int row  = base0 + it * 16 + l;
        const int rowc = row < NROWS ? row : NROWS - 1;
        // B-frags: B[k = q*8+j+32kc][n = l] = E[row][k]
        const float4* ep = (const float4*)E + (size_t)rowc * 32 + q * 2;
        bf16x8 Bf[4];
#pragma unroll
        for (int kc = 0; kc < 4; ++kc)
            Bf[kc] = pack8(ep[kc * 8], ep[kc * 8 + 1]);

        f32x4 D[4];
#pragma unroll
        for (int mt = 0; mt < 4; ++mt) { f32x4 z = {0.f, 0.f, 0.f, 0.f}; D[mt] = z; }
#pragma unroll
        for (int kc = 0; kc < 4; ++kc)
#pragma unroll
            for (int mt = 0; mt < 4; ++mt)
                D[mt] = __builtin_amdgcn_mfma_f32_16x16x32_bf16(Af[mt][kc], Bf[kc], D[mt], 0, 0, 0);

        if (row < NROWS) {
#pragma unroll
            for (int mt = 0; mt < 4; ++mt) {
                float v0 = expf(D[mt][0]), v1 = expf(D[mt][1]);
                float v2 = expf(D[mt][2]), v3 = expf(D[mt][3]);
                if (mt == 3 && q == 3) { v2 = 0.f; v3 = 0.f; }   // tags 62, 63
                uint2 o; o.x = pack_bf2(v0, v1); o.y = pack_bf2(v2, v3);
                Btb[(size_t)row * 16 + mt * 4 + q] = o;          // [w][tag] bf16
            }
        }
    }
}

// ---------------------------------------------------------------------------
// Kernel 2: fwd/bwd recurrence, fully in registers.
// State X = B-operand: X[tag = kc*16+q*4+j][sent = l], bf16x4 per kc.
// fwd (wv=0): A = S^T (mask on m), X' = (S^T X) o e_t, t = 2..127.
// bwd (wv=1): A = S   (mask on k), X' = e_t o (S X),  t = 253..128.
// D[mt] tag set == B-frag[kc=mt] K set -> register handoff, no LDS per step.
// Emission ring: 6 bf16 buffers; words fetched 12 steps ahead (all in-bounds).
// asm memory clobber after each substep's loads pins them (no sinking).
// Join: z = (S^T alpha_127) . (e_128 o q_129) via one LDS tile + dot.
// ---------------------------------------------------------------------------
__global__ __launch_bounds__(128, 1) void crf_fwdbwd(
    const int* __restrict__ words, const float* __restrict__ WA,
    const uint2* __restrict__ Btb, float* __restrict__ out)
{
    __shared__ float ytile[16 * 68];
    const int lane  = threadIdx.x & 63;
    const int wv    = threadIdx.x >> 6;          // 0 = fwd, 1 = bwd
    const int l     = lane & 15;
    const int q     = lane >> 4;
    const int sbase = blockIdx.x * 16;

    // Transition A-frags. S[i][j] = exp(WA[i][j]) * (j != BOS)/64.
    bf16x4 Sf[4][4];
#pragma unroll
    for (int mt = 0; mt < 4; ++mt)
#pragma unroll
        for (int kc = 0; kc < 4; ++kc) {
            float t[4];
#pragma unroll
            for (int j = 0; j < 4; ++j) {
                const int mg = mt * 16 + l;          // m index
                const int kg = kc * 16 + q * 4 + j;  // k index
                const int ii = wv ? mg : kg;         // WA row
                const int jj = wv ? kg : mg;         // WA col (masked: S's j)
                t[j] = (jj == BOS_T) ? 0.f : expf(WA[ii * 64 + jj]) * 0.015625f;
            }
            Sf[mt][kc] = pack4(t[0], t[1], t[2], t[3]);
        }

    // Init vector in X-layout, tag jt = kc*16 + q*4 + e:
    // fwd: S[BOS][jt] (alpha_1 pre-emission); bwd: S[jt][EOS] (q_255).
    float g[4][4];
#pragma unroll
    for (int kc = 0; kc < 4; ++kc)
#pragma unroll
        for (int e = 0; e < 4; ++e) {
            const int jt = kc * 16 + q * 4 + e;
            g[kc][e] = wv ? expf(WA[jt * 64 + EOS_T]) * 0.015625f
                          : ((jt == BOS_T) ? 0.f : expf(WA[BOS_T * 64 + jt]) * 0.015625f);
        }

    const int wb   = (sbase + l) * TLEN;
    const int tdir = wv ? -1 : 1;
    const int t0   = wv ? 254 : 1;

    auto eload = [&](int w, uint2 (&buf)[4]) {
#pragma unroll
        for (int kc = 0; kc < 4; ++kc)
            buf[kc] = Btb[(size_t)w * 16 + kc * 4 + q];
    };

    uint2 ei[4], ebA[4], ebB[4], ebC[4], ebD[4], ebE[4], ebF[4];
    eload(words[wb + t0], ei);
    eload(words[wb + t0 + 1 * tdir], ebA);   // emis for step 0
    eload(words[wb + t0 + 2 * tdir], ebB);
    eload(words[wb + t0 + 3 * tdir], ebC);
    eload(words[wb + t0 + 4 * tdir], ebD);
    eload(words[wb + t0 + 5 * tdir], ebE);
    eload(words[wb + t0 + 6 * tdir], ebF);   // emis for step 5
    int wdA = words[wb + t0 + 7 * tdir];     // word for step 6
    int wdB = words[wb + t0 + 8 * tdir];
    int wdC = words[wb + t0 + 9 * tdir];
    int wdD = words[wb + t0 + 10 * tdir];
    int wdE = words[wb + t0 + 11 * tdir];
    int wdF = words[wb + t0 + 12 * tdir];    // word for step 11
    asm volatile("" ::: "memory");           // pin prologue loads here

    // X init = g o e_{t0}
    bf16x4 X[4];
#pragma unroll
    for (int kc = 0; kc < 4; ++kc) {
        float f0 = __uint_as_float(ei[kc].x << 16)         * g[kc][0];
        float f1 = __uint_as_float(ei[kc].x & 0xffff0000u) * g[kc][1];
        float f2 = __uint_as_float(ei[kc].y << 16)         * g[kc][2];
        float f3 = __uint_as_float(ei[kc].y & 0xffff0000u) * g[kc][3];
        X[kc] = pack4(f0, f1, f2, f3);
    }

    float xf[4][4];                          // last step's f32 products (join)

    // substep consuming step i: refills eb for step i+6, fetches word i+12.
    // memory clobber at the end forbids sinking this substep's loads into
    // later substeps (keeps the ring 6 deep at codegen level).
    auto substep = [&](uint2 (&eb)[4], int& wd, int widx) {
        f32x4 D[4];
#pragma unroll
        for (int mt = 0; mt < 4; ++mt) { f32x4 z = {0.f, 0.f, 0.f, 0.f}; D[mt] = z; }
#pragma unroll
        for (int kc = 0; kc < 4; ++kc)
#pragma unroll
            for (int mt = 0; mt < 4; ++mt)
                D[mt] = __builtin_amdgcn_mfma_f32_16x16x16bf16_1k(Sf[mt][kc], X[kc], D[mt], 0, 0, 0);
#pragma unroll
        for (int kc = 0; kc < 4; ++kc) {
            float f0 = __uint_as_float(eb[kc].x << 16);
            float f1 = __uint_as_float(eb[kc].x & 0xffff0000u);
            float f2 = __uint_as_float(eb[kc].y << 16);
            float f3 = __uint_as_float(eb[kc].y & 0xffff0000u);
            xf[kc][0] = D[kc][0] * f0;  xf[kc][1] = D[kc][1] * f1;
            xf[kc][2] = D[kc][2] * f2;  xf[kc][3] = D[kc][3] * f3;
            X[kc] = pack4(xf[kc][0], xf[kc][1], xf[kc][2], xf[kc][3]);
        }
        eload(wd, eb);
        wd = words[wb + widx];
        asm volatile("" ::: "memory");
    };

    // 126 steps; word index bounds: fwd max t0+139=140<256, bwd min 254-138>=0
    for (int i = 0; i < 126; i += 6) {
        substep(ebA, wdA, t0 + tdir * (i + 13));
        substep(ebB, wdB, t0 + tdir * (i + 14));
        substep(ebC, wdC, t0 + tdir * (i + 15));
        substep(ebD, wdD, t0 + tdir * (i + 16));
        substep(ebE, wdE, t0 + tdir * (i + 17));
        substep(ebF, wdF, t0 + tdir * (i + 18));
    }

    if (wv == 0) {
        // extra step: Y = S^T alpha_127 (no emission) -> LDS
        f32x4 D[4];
#pragma unroll
        for (int mt = 0; mt < 4; ++mt) { f32x4 z = {0.f, 0.f, 0.f, 0.f}; D[mt] = z; }
#pragma unroll
        for (int kc = 0; kc < 4; ++kc)
#pragma unroll
            for (int mt = 0; mt < 4; ++mt)
                D[mt] = __builtin_amdgcn_mfma_f32_16x16x16bf16_1k(Sf[mt][kc], X[kc], D[mt], 0, 0, 0);
#pragma unroll
        for (int mt = 0; mt < 4; ++mt) {
            float4 o = {D[mt][0], D[mt][1], D[mt][2], D[mt][3]};
            *(float4*)&ytile[l * 68 + mt * 16 + q * 4] = o;
        }
    }
    __syncthreads();
    if (wv == 1) {
        // z[s] = sum_tag Y[tag][s] * X128[tag][s]
        float p = 0.f;
#pragma unroll
        for (int mt = 0; mt < 4; ++mt)
#pragma unroll
            for (int r = 0; r < 4; ++r)
                p = fmaf(ytile[l * 68 + mt * 16 + q * 4 + r], xf[mt][r], p);
        p += __shfl_xor(p, 16, 64);
        p += __shfl_xor(p, 32, 64);
        if (lane < 16)
            out[sbase + l] = logf(p) + 255.0f * LOG64;
    }
}

extern "C" void kernel_launch(void* const* d_in, const int* in_sizes, int n_in,
                              void* d_out, int out_size, void* d_ws, size_t ws_size,
                              hipStream_t stream) {
    const int*   words  = (const int*)d_in[0];
    const float* ThetaB = (const float*)d_in[1];
    const float* WA     = (const float*)d_in[2];
    const float* E      = (const float*)d_in[3];
    float*       outp   = (float*)d_out;
    uint2*       Btb    = (uint2*)d_ws;          // 50002*128 B = 6.4 MB

    // 782 blocks x 1 wave x 4 word-tiles = 50048 >= 50002 rows
    emis_mfma<<<dim3(782), dim3(64), 0, stream>>>(ThetaB, E, Btb);
    // 128 blocks x (fwd wave + bwd wave), 16 sentences each
    crf_fwdbwd<<<dim3(128), dim3(128), 0, stream>>>(words, WA, Btb, outp);
}

// Round 3
// 128.147 us; speedup vs baseline: 1.1508x; 1.0119x over previous
//
#include <hip/hip_runtime.h>

// CRF forward logZ. Inputs: words i32 [2048][256], ThetaB f32 [64][128],
// WA f32 [64][64], E f32 [50002][128]. out: f32 [2048].
// ws: Bt table in bf16, [50002][64] = 6.4 MB.
//
// R8: crf_fwdbwd emission ring rebuilt as MANUAL INLINE-ASM loads with
//     counted s_waitcnt. R6 (__launch_bounds__) and R7 (memory clobber)
//     both failed to keep the 6-deep ring live (VGPR 68/80 < ~140 live set;
//     932 cy/step = one serial gather latency each step): LLVM treats the
//     const __restrict__ Btb loads as invariant and sinks them across
//     clobbers. asm volatile loads are structurally unsinkable.
//     Issue pattern is uniform (5 VMEM/substep: 4 gathers + 1 word), so the
//     top-of-substep wait is a constant vmcnt(25) = "6-back group done".
//     sched_barrier(0) after each wait stops MFMA/VALU hoisting (rule #18).

#define NROWS 50002
#define EOS_T 62
#define BOS_T 63
#define TLEN  256
#define LOG64 4.1588830833596715f

typedef __attribute__((ext_vector_type(4))) short bf16x4;
typedef __attribute__((ext_vector_type(8))) short bf16x8;
typedef __attribute__((ext_vector_type(4))) float f32x4;
typedef __attribute__((ext_vector_type(2))) unsigned int u32x2;

// round-half-up f32->bf16 pair pack (2 add + 1 perm); lo in low 16 bits
static __device__ __forceinline__ unsigned pack_bf2(float lo, float hi) {
    unsigned a = __float_as_uint(lo) + 0x8000u;
    unsigned b = __float_as_uint(hi) + 0x8000u;
    return __builtin_amdgcn_perm(b, a, 0x07060302u);
}
static __device__ __forceinline__ bf16x8 pack8(float4 a, float4 b) {
    union { bf16x8 v; unsigned u[4]; } r;
    r.u[0] = pack_bf2(a.x, a.y); r.u[1] = pack_bf2(a.z, a.w);
    r.u[2] = pack_bf2(b.x, b.y); r.u[3] = pack_bf2(b.z, b.w);
    return r.v;
}
static __device__ __forceinline__ bf16x4 pack4(float f0, float f1, float f2, float f3) {
    union { bf16x4 v; unsigned u[2]; } r;
    r.u[0] = pack_bf2(f0, f1); r.u[1] = pack_bf2(f2, f3);
    return r.v;
}

// 4 row-gather loads (32B of one Btb row, this lane's q-slice) — asm volatile:
// unsinkable, unreorderable; early-clobber so dests never alias the addr pair.
#define GLOAD4(buf, addr)                                                     \
    asm volatile("global_load_dwordx2 %0, %4, off\n\t"                        \
                 "global_load_dwordx2 %1, %4, off offset:32\n\t"              \
                 "global_load_dwordx2 %2, %4, off offset:64\n\t"              \
                 "global_load_dwordx2 %3, %4, off offset:96"                  \
                 : "=&v"(buf[0]), "=&v"(buf[1]), "=&v"(buf[2]), "=&v"(buf[3]) \
                 : "v"(addr))
#define WLOAD(wd, addr)                                                       \
    asm volatile("global_load_dword %0, %1, off" : "=&v"(wd) : "v"(addr))
#define SWAIT(n)                                                              \
    do { asm volatile("s_waitcnt vmcnt(" #n ")");                             \
         __builtin_amdgcn_sched_barrier(0); } while (0)

// ---------------------------------------------------------------------------
// Kernel 1: Btb[w][k] = bf16(exp(ThetaB[k].E[w])); tags 62,63 -> 0.
// MFMA GEMM, D[tag = mt*16+q*4+r][word = l]. A = ThetaB (constant per wave,
// amortized over 4 word-tiles), B = E rows loaded in native fragment layout.
// ---------------------------------------------------------------------------
__global__ __launch_bounds__(64) void emis_mfma(
    const float* __restrict__ ThetaB, const float* __restrict__ E,
    uint2* __restrict__ Btb)
{
    const int l = threadIdx.x & 15;
    const int q = threadIdx.x >> 4;

    // A-frags: A[m=l -> tag mt*16+l][k = q*8+j+32kc] = ThetaB[tag][k]
    bf16x8 Af[4][4];
#pragma unroll
    for (int mt = 0; mt < 4; ++mt)
#pragma unroll
        for (int kc = 0; kc < 4; ++kc) {
            const float4* tp = (const float4*)ThetaB + (mt * 16 + l) * 32 + kc * 8 + q * 2;
            Af[mt][kc] = pack8(tp[0], tp[1]);
        }

    const int base0 = blockIdx.x * 64;
#pragma unroll
    for (int it = 0; it < 4; ++it) {
        const int row  = base0 + it * 16 + l;
        const int rowc = row < NROWS ? row : NROWS - 1;
        // B-frags: B[k = q*8+j+32kc][n = l] = E[row][k]
        const float4* ep = (const float4*)E + (size_t)rowc * 32 + q * 2;
        bf16x8 Bf[4];
#pragma unroll
        for (int kc = 0; kc < 4; ++kc)
            Bf[kc] = pack8(ep[kc * 8], ep[kc * 8 + 1]);

        f32x4 D[4];
#pragma unroll
        for (int mt = 0; mt < 4; ++mt) { f32x4 z = {0.f, 0.f, 0.f, 0.f}; D[mt] = z; }
#pragma unroll
        for (int kc = 0; kc < 4; ++kc)
#pragma unroll
            for (int mt = 0; mt < 4; ++mt)
                D[mt] = __builtin_amdgcn_mfma_f32_16x16x32_bf16(Af[mt][kc], Bf[kc], D[mt], 0, 0, 0);

        if (row < NROWS) {
#pragma unroll
            for (int mt = 0; mt < 4; ++mt) {
                float v0 = expf(D[mt][0]), v1 = expf(D[mt][1]);
                float v2 = expf(D[mt][2]), v3 = expf(D[mt][3]);
                if (mt == 3 && q == 3) { v2 = 0.f; v3 = 0.f; }   // tags 62, 63
                uint2 o; o.x = pack_bf2(v0, v1); o.y = pack_bf2(v2, v3);
                Btb[(size_t)row * 16 + mt * 4 + q] = o;          // [w][tag] bf16
            }
        }
    }
}

// ---------------------------------------------------------------------------
// Kernel 2: fwd/bwd recurrence, fully in registers.
// State X = B-operand: X[tag = kc*16+q*4+j][sent = l], bf16x4 per kc.
// fwd (wv=0): A = S^T (mask on m), X' = (S^T X) o e_t, t = 2..127.
// bwd (wv=1): A = S   (mask on k), X' = e_t o (S X),  t = 253..128.
// D[mt] tag set == B-frag[kc=mt] K set -> register handoff, no LDS per step.
// Emission ring: 6 asm-load buffers, words 12 steps ahead; per-substep
// s_waitcnt vmcnt(25) drains exactly the 6-back issue group (4G+1W).
// Join: z = (S^T alpha_127) . (e_128 o q_129) via one LDS tile + dot.
// ---------------------------------------------------------------------------
__global__ __launch_bounds__(128, 1) void crf_fwdbwd(
    const int* __restrict__ words, const float* __restrict__ WA,
    const uint2* __restrict__ Btb, float* __restrict__ out)
{
    __shared__ float ytile[16 * 68];
    const int lane  = threadIdx.x & 63;
    const int wv    = threadIdx.x >> 6;          // 0 = fwd, 1 = bwd
    const int l     = lane & 15;
    const int q     = lane >> 4;
    const int sbase = blockIdx.x * 16;

    // Transition A-frags. S[i][j] = exp(WA[i][j]) * (j != BOS)/64.
    bf16x4 Sf[4][4];
#pragma unroll
    for (int mt = 0; mt < 4; ++mt)
#pragma unroll
        for (int kc = 0; kc < 4; ++kc) {
            float t[4];
#pragma unroll
            for (int j = 0; j < 4; ++j) {
                const int mg = mt * 16 + l;          // m index
                const int kg = kc * 16 + q * 4 + j;  // k index
                const int ii = wv ? mg : kg;         // WA row
                const int jj = wv ? kg : mg;         // WA col (masked: S's j)
                t[j] = (jj == BOS_T) ? 0.f : expf(WA[ii * 64 + jj]) * 0.015625f;
            }
            Sf[mt][kc] = pack4(t[0], t[1], t[2], t[3]);
        }

    // Init vector in X-layout, tag jt = kc*16 + q*4 + e:
    // fwd: S[BOS][jt] (alpha_1 pre-emission); bwd: S[jt][EOS] (q_255).
    float g[4][4];
#pragma unroll
    for (int kc = 0; kc < 4; ++kc)
#pragma unroll
        for (int e = 0; e < 4; ++e) {
            const int jt = kc * 16 + q * 4 + e;
            g[kc][e] = wv ? expf(WA[jt * 64 + EOS_T]) * 0.015625f
                          : ((jt == BOS_T) ? 0.f : expf(WA[BOS_T * 64 + jt]) * 0.015625f);
        }

    const int wb   = (sbase + l) * TLEN;
    const int tdir = wv ? -1 : 1;
    const int t0   = wv ? 254 : 1;

    const unsigned long long btbp   = (unsigned long long)(const char*)Btb + (unsigned)(q * 8);
    const int*               wordsp = words + wb;

    // -------- prologue: 13 words via normal loads, then asm-issue region ----
    const int w0  = wordsp[t0];
    const int w1  = wordsp[t0 + 1 * tdir],  w2  = wordsp[t0 + 2 * tdir];
    const int w3  = wordsp[t0 + 3 * tdir],  w4  = wordsp[t0 + 4 * tdir];
    const int w5  = wordsp[t0 + 5 * tdir],  w6  = wordsp[t0 + 6 * tdir];

    unsigned long long aI = btbp + (unsigned long long)w0 * 128u;
    unsigned long long aA = btbp + (unsigned long long)w1 * 128u;
    unsigned long long aB = btbp + (unsigned long long)w2 * 128u;
    unsigned long long aC = btbp + (unsigned long long)w3 * 128u;
    unsigned long long aD = btbp + (unsigned long long)w4 * 128u;
    unsigned long long aE = btbp + (unsigned long long)w5 * 128u;
    unsigned long long aF = btbp + (unsigned long long)w6 * 128u;

    // drain ALL compiler-issued vmem so manual vmcnt counts are exact
    asm volatile("s_waitcnt vmcnt(0) lgkmcnt(0)");
    __builtin_amdgcn_sched_barrier(0);

    u32x2 ei[4], ebA[4], ebB[4], ebC[4], ebD[4], ebE[4], ebF[4];
    int wdA, wdB, wdC, wdD, wdE, wdF;
    // uniform issue groups: [ei:4], then 6x [4 gathers + 1 word] = 34 ops
    GLOAD4(ei, aI);
    GLOAD4(ebA, aA); WLOAD(wdA, (unsigned long long)(wordsp + t0 + 7  * tdir));
    GLOAD4(ebB, aB); WLOAD(wdB, (unsigned long long)(wordsp + t0 + 8  * tdir));
    GLOAD4(ebC, aC); WLOAD(wdC, (unsigned long long)(wordsp + t0 + 9  * tdir));
    GLOAD4(ebD, aD); WLOAD(wdD, (unsigned long long)(wordsp + t0 + 10 * tdir));
    GLOAD4(ebE, aE); WLOAD(wdE, (unsigned long long)(wordsp + t0 + 11 * tdir));
    GLOAD4(ebF, aF); WLOAD(wdF, (unsigned long long)(wordsp + t0 + 12 * tdir));

    SWAIT(30);                                   // ei (oldest 4) complete

    // X init = g o e_{t0}
    bf16x4 X[4];
#pragma unroll
    for (int kc = 0; kc < 4; ++kc) {
        float f0 = __uint_as_float(ei[kc][0] << 16)         * g[kc][0];
        float f1 = __uint_as_float(ei[kc][0] & 0xffff0000u) * g[kc][1];
        float f2 = __uint_as_float(ei[kc][1] << 16)         * g[kc][2];
        float f3 = __uint_as_float(ei[kc][1] & 0xffff0000u) * g[kc][3];
        X[kc] = pack4(f0, f1, f2, f3);
    }

    float xf[4][4];                              // last step's f32 products

    // substep consuming its eb (loaded 6 back) and wd (loaded 6 back);
    // refills eb for +6, fetches word for +12. Exactly 5 asm VMEM issued.
    auto substep = [&](u32x2 (&eb)[4], int& wd, int widx) {
        SWAIT(25);                               // 6-back group (4G+1W) done
        f32x4 D[4];
#pragma unroll
        for (int mt = 0; mt < 4; ++mt) { f32x4 z = {0.f, 0.f, 0.f, 0.f}; D[mt] = z; }
#pragma unroll
        for (int kc = 0; kc < 4; ++kc)
#pragma unroll
            for (int mt = 0; mt < 4; ++mt)
                D[mt] = __builtin_amdgcn_mfma_f32_16x16x16bf16_1k(Sf[mt][kc], X[kc], D[mt], 0, 0, 0);
#pragma unroll
        for (int kc = 0; kc < 4; ++kc) {
            float f0 = __uint_as_float(eb[kc][0] << 16);
            float f1 = __uint_as_float(eb[kc][0] & 0xffff0000u);
            float f2 = __uint_as_float(eb[kc][1] << 16);
            float f3 = __uint_as_float(eb[kc][1] & 0xffff0000u);
            xf[kc][0] = D[kc][0] * f0;  xf[kc][1] = D[kc][1] * f1;
            xf[kc][2] = D[kc][2] * f2;  xf[kc][3] = D[kc][3] * f3;
            X[kc] = pack4(xf[kc][0], xf[kc][1], xf[kc][2], xf[kc][3]);
        }
        unsigned long long a = btbp + (unsigned long long)wd * 128u;
        GLOAD4(eb, a);
        WLOAD(wd, (unsigned long long)(wordsp + widx));
    };

    // 126 steps; word index bounds: fwd max t0+138=139<256, bwd min 254-138>=0
    for (int i = 0; i < 126; i += 6) {
        substep(ebA, wdA, t0 + tdir * (i + 13));
        substep(ebB, wdB, t0 + tdir * (i + 14));
        substep(ebC, wdC, t0 + tdir * (i + 15));
        substep(ebD, wdD, t0 + tdir * (i + 16));
        substep(ebE, wdE, t0 + tdir * (i + 17));
        substep(ebF, wdF, t0 + tdir * (i + 18));
    }

    if (wv == 0) {
        // extra step: Y = S^T alpha_127 (no emission) -> LDS
        f32x4 D[4];
#pragma unroll
        for (int mt = 0; mt < 4; ++mt) { f32x4 z = {0.f, 0.f, 0.f, 0.f}; D[mt] = z; }
#pragma unroll
        for (int kc = 0; kc < 4; ++kc)
#pragma unroll
            for (int mt = 0; mt < 4; ++mt)
                D[mt] = __builtin_amdgcn_mfma_f32_16x16x16bf16_1k(Sf[mt][kc], X[kc], D[mt], 0, 0, 0);
#pragma unroll
        for (int mt = 0; mt < 4; ++mt) {
            float4 o = {D[mt][0], D[mt][1], D[mt][2], D[mt][3]};
            *(float4*)&ytile[l * 68 + mt * 16 + q * 4] = o;
        }
    }
    __syncthreads();
    if (wv == 1) {
        // z[s] = sum_tag Y[tag][s] * X128[tag][s]
        float p = 0.f;
#pragma unroll
        for (int mt = 0; mt < 4; ++mt)
#pragma unroll
            for (int r = 0; r < 4; ++r)
                p = fmaf(ytile[l * 68 + mt * 16 + q * 4 + r], xf[mt][r], p);
        p += __shfl_xor(p, 16, 64);
        p += __shfl_xor(p, 32, 64);
        if (lane < 16)
            out[sbase + l] = logf(p) + 255.0f * LOG64;
    }
}

extern "C" void kernel_launch(void* const* d_in, const int* in_sizes, int n_in,
                              void* d_out, int out_size, void* d_ws, size_t ws_size,
                              hipStream_t stream) {
    const int*   words  = (const int*)d_in[0];
    const float* ThetaB = (const float*)d_in[1];
    const float* WA     = (const float*)d_in[2];
    const float* E      = (const float*)d_in[3];
    float*       outp   = (float*)d_out;
    uint2*       Btb    = (uint2*)d_ws;          // 50002*128 B = 6.4 MB

    // 782 blocks x 1 wave x 4 word-tiles = 50048 >= 50002 rows
    emis_mfma<<<dim3(782), dim3(64), 0, stream>>>(ThetaB, E, Btb);
    // 128 blocks x (fwd wave + bwd wave), 16 sentences each
    crf_fwdbwd<<<dim3(128), dim3(128), 0, stream>>>(words, WA, Btb, outp);
}

// Round 4
// 118.051 us; speedup vs baseline: 1.2492x; 1.0855x over previous
//
#include <hip/hip_runtime.h>

// CRF forward logZ. Inputs: words i32 [2048][256], ThetaB f32 [64][128],
// WA f32 [64][64], E f32 [50002][128]. out: f32 [2048].
// ws: Bt table in bf16, [50002][64] = 6.4 MB, row layout [w][q][kc].
//
// R9: R8's structural asm ring STILL stalled ~740cy/step: 5 divergent VMEM
//     instrs/step (4x dwordx2 gather + word) = ~80 line-requests/step; 30
//     outstanding instrs ~ 1900 requests/wave >> per-CU MSHR tracking, so
//     groups queued at the CU instead of overlapping (nominal ring depth not
//     realized). Fix: (1) Btb row TRANSPOSED to [w][q][kc] -> per-lane 32B
//     contiguous -> 2x global_load_dwordx4 per gather (3 VMEM/step, 8
//     requests/row); (2) ring depth 9 (126=14x9), constant vmcnt(24);
//     (3) MFMA block issued BEFORE the wait (needs only X regs).

#define NROWS 50002
#define EOS_T 62
#define BOS_T 63
#define TLEN  256
#define LOG64 4.1588830833596715f

typedef __attribute__((ext_vector_type(4))) short bf16x4;
typedef __attribute__((ext_vector_type(8))) short bf16x8;
typedef __attribute__((ext_vector_type(4))) float f32x4;
typedef __attribute__((ext_vector_type(4))) unsigned int u32x4;

// round-half-up f32->bf16 pair pack (2 add + 1 perm); lo in low 16 bits
static __device__ __forceinline__ unsigned pack_bf2(float lo, float hi) {
    unsigned a = __float_as_uint(lo) + 0x8000u;
    unsigned b = __float_as_uint(hi) + 0x8000u;
    return __builtin_amdgcn_perm(b, a, 0x07060302u);
}
static __device__ __forceinline__ bf16x8 pack8(float4 a, float4 b) {
    union { bf16x8 v; unsigned u[4]; } r;
    r.u[0] = pack_bf2(a.x, a.y); r.u[1] = pack_bf2(a.z, a.w);
    r.u[2] = pack_bf2(b.x, b.y); r.u[3] = pack_bf2(b.z, b.w);
    return r.v;
}
static __device__ __forceinline__ bf16x4 pack4(float f0, float f1, float f2, float f3) {
    union { bf16x4 v; unsigned u[2]; } r;
    r.u[0] = pack_bf2(f0, f1); r.u[1] = pack_bf2(f2, f3);
    return r.v;
}

// one Btb row slice for this lane: 32 contiguous bytes = 2x dwordx4.
// asm volatile: unsinkable; early-clobber so dests don't alias addr pair.
#define GLOAD2(buf, addr)                                                     \
    asm volatile("global_load_dwordx4 %0, %2, off\n\t"                        \
                 "global_load_dwordx4 %1, %2, off offset:16"                  \
                 : "=&v"(buf[0]), "=&v"(buf[1]) : "v"(addr))
#define WLOAD(wd, addr)                                                       \
    asm volatile("global_load_dword %0, %1, off" : "=&v"(wd) : "v"(addr))
#define SWAIT(n)                                                              \
    do { __builtin_amdgcn_sched_barrier(0);                                   \
         asm volatile("s_waitcnt vmcnt(" #n ")");                             \
         __builtin_amdgcn_sched_barrier(0); } while (0)

// ---------------------------------------------------------------------------
// Kernel 1: Btb[w][q*4+kc] = bf16(exp(ThetaB[tag].E[w])); tags 62,63 -> 0.
// MFMA GEMM, D[tag = mt*16+q*4+r][word = l]. A = ThetaB (constant per wave,
// amortized over 4 word-tiles), B = E rows loaded in native fragment layout.
// Store index q*4+mt (transposed) so crf lanes read 32B contiguous.
// ---------------------------------------------------------------------------
__global__ __launch_bounds__(64) void emis_mfma(
    const float* __restrict__ ThetaB, const float* __restrict__ E,
    uint2* __restrict__ Btb)
{
    const int l = threadIdx.x & 15;
    const int q = threadIdx.x >> 4;

    // A-frags: A[m=l -> tag mt*16+l][k = q*8+j+32kc] = ThetaB[tag][k]
    bf16x8 Af[4][4];
#pragma unroll
    for (int mt = 0; mt < 4; ++mt)
#pragma unroll
        for (int kc = 0; kc < 4; ++kc) {
            const float4* tp = (const float4*)ThetaB + (mt * 16 + l) * 32 + kc * 8 + q * 2;
            Af[mt][kc] = pack8(tp[0], tp[1]);
        }

    const int base0 = blockIdx.x * 64;
#pragma unroll
    for (int it = 0; it < 4; ++it) {
        const int row  = base0 + it * 16 + l;
        const int rowc = row < NROWS ? row : NROWS - 1;
        // B-frags: B[k = q*8+j+32kc][n = l] = E[row][k]
        const float4* ep = (const float4*)E + (size_t)rowc * 32 + q * 2;
        bf16x8 Bf[4];
#pragma unroll
        for (int kc = 0; kc < 4; ++kc)
            Bf[kc] = pack8(ep[kc * 8], ep[kc * 8 + 1]);

        f32x4 D[4];
#pragma unroll
        for (int mt = 0; mt < 4; ++mt) { f32x4 z = {0.f, 0.f, 0.f, 0.f}; D[mt] = z; }
#pragma unroll
        for (int kc = 0; kc < 4; ++kc)
#pragma unroll
            for (int mt = 0; mt < 4; ++mt)
                D[mt] = __builtin_amdgcn_mfma_f32_16x16x32_bf16(Af[mt][kc], Bf[kc], D[mt], 0, 0, 0);

        if (row < NROWS) {
#pragma unroll
            for (int mt = 0; mt < 4; ++mt) {
                float v0 = expf(D[mt][0]), v1 = expf(D[mt][1]);
                float v2 = expf(D[mt][2]), v3 = expf(D[mt][3]);
                if (mt == 3 && q == 3) { v2 = 0.f; v3 = 0.f; }   // tags 62, 63
                uint2 o; o.x = pack_bf2(v0, v1); o.y = pack_bf2(v2, v3);
                Btb[(size_t)row * 16 + q * 4 + mt] = o;          // transposed
            }
        }
    }
}

// ---------------------------------------------------------------------------
// Kernel 2: fwd/bwd recurrence, fully in registers.
// State X = B-operand: X[tag = kc*16+q*4+j][sent = l], bf16x4 per kc.
// fwd (wv=0): A = S^T (mask on m), X' = (S^T X) o e_t, t = 2..127.
// bwd (wv=1): A = S   (mask on k), X' = e_t o (S X),  t = 253..128.
// Emission ring: 9 asm-load groups of 3 VMEM (2x dwordx4 gather + 1 word,
// word fetched 18 steps ahead); per-substep wait = constant vmcnt(24).
// Join: z = (S^T alpha_127) . (e_128 o q_129) via one LDS tile + dot.
// ---------------------------------------------------------------------------
__global__ __launch_bounds__(128, 1) void crf_fwdbwd(
    const int* __restrict__ words, const float* __restrict__ WA,
    const uint2* __restrict__ Btb, float* __restrict__ out)
{
    __shared__ float ytile[16 * 68];
    const int lane  = threadIdx.x & 63;
    const int wv    = threadIdx.x >> 6;          // 0 = fwd, 1 = bwd
    const int l     = lane & 15;
    const int q     = lane >> 4;
    const int sbase = blockIdx.x * 16;

    // Transition A-frags. S[i][j] = exp(WA[i][j]) * (j != BOS)/64.
    bf16x4 Sf[4][4];
#pragma unroll
    for (int mt = 0; mt < 4; ++mt)
#pragma unroll
        for (int kc = 0; kc < 4; ++kc) {
            float t[4];
#pragma unroll
            for (int j = 0; j < 4; ++j) {
                const int mg = mt * 16 + l;          // m index
                const int kg = kc * 16 + q * 4 + j;  // k index
                const int ii = wv ? mg : kg;         // WA row
                const int jj = wv ? kg : mg;         // WA col (masked: S's j)
                t[j] = (jj == BOS_T) ? 0.f : expf(WA[ii * 64 + jj]) * 0.015625f;
            }
            Sf[mt][kc] = pack4(t[0], t[1], t[2], t[3]);
        }

    // Init vector in X-layout, tag jt = kc*16 + q*4 + e:
    // fwd: S[BOS][jt] (alpha_1 pre-emission); bwd: S[jt][EOS] (q_255).
    float g[4][4];
#pragma unroll
    for (int kc = 0; kc < 4; ++kc)
#pragma unroll
        for (int e = 0; e < 4; ++e) {
            const int jt = kc * 16 + q * 4 + e;
            g[kc][e] = wv ? expf(WA[jt * 64 + EOS_T]) * 0.015625f
                          : ((jt == BOS_T) ? 0.f : expf(WA[BOS_T * 64 + jt]) * 0.015625f);
        }

    const int wb   = (sbase + l) * TLEN;
    const int tdir = wv ? -1 : 1;
    const int t0   = wv ? 254 : 1;

    // lane's 32B slice of a Btb row starts at byte q*32
    const unsigned long long btbp   = (unsigned long long)(const char*)Btb + (unsigned)(q * 32);
    const int*               wordsp = words + wb;

    // -------- prologue: 10 words via normal loads, then asm-issue region ----
    const int w0 = wordsp[t0];
    const int w1 = wordsp[t0 + 1 * tdir], w2 = wordsp[t0 + 2 * tdir];
    const int w3 = wordsp[t0 + 3 * tdir], w4 = wordsp[t0 + 4 * tdir];
    const int w5 = wordsp[t0 + 5 * tdir], w6 = wordsp[t0 + 6 * tdir];
    const int w7 = wordsp[t0 + 7 * tdir], w8 = wordsp[t0 + 8 * tdir];
    const int w9 = wordsp[t0 + 9 * tdir];

    unsigned long long aI0 = btbp + (unsigned long long)w0 * 128u;
    unsigned long long aA = btbp + (unsigned long long)w1 * 128u;
    unsigned long long aB = btbp + (unsigned long long)w2 * 128u;
    unsigned long long aC = btbp + (unsigned long long)w3 * 128u;
    unsigned long long aD = btbp + (unsigned long long)w4 * 128u;
    unsigned long long aE = btbp + (unsigned long long)w5 * 128u;
    unsigned long long aF = btbp + (unsigned long long)w6 * 128u;
    unsigned long long aG = btbp + (unsigned long long)w7 * 128u;
    unsigned long long aH = btbp + (unsigned long long)w8 * 128u;
    unsigned long long aJ = btbp + (unsigned long long)w9 * 128u;

    // drain ALL compiler-issued vmem so manual vmcnt counts are exact
    asm volatile("s_waitcnt vmcnt(0) lgkmcnt(0)");
    __builtin_amdgcn_sched_barrier(0);

    u32x4 ei[2], ebA[2], ebB[2], ebC[2], ebD[2], ebE[2], ebF[2], ebG[2], ebH[2], ebI[2];
    int wdA, wdB, wdC, wdD, wdE, wdF, wdG, wdH, wdI;
    // issue groups: [ei:2], then 9x [2 gathers + 1 word] = 29 ops
    GLOAD2(ei, aI0);
    GLOAD2(ebA, aA); WLOAD(wdA, (unsigned long long)(wordsp + t0 + 10 * tdir));
    GLOAD2(ebB, aB); WLOAD(wdB, (unsigned long long)(wordsp + t0 + 11 * tdir));
    GLOAD2(ebC, aC); WLOAD(wdC, (unsigned long long)(wordsp + t0 + 12 * tdir));
    GLOAD2(ebD, aD); WLOAD(wdD, (unsigned long long)(wordsp + t0 + 13 * tdir));
    GLOAD2(ebE, aE); WLOAD(wdE, (unsigned long long)(wordsp + t0 + 14 * tdir));
    GLOAD2(ebF, aF); WLOAD(wdF, (unsigned long long)(wordsp + t0 + 15 * tdir));
    GLOAD2(ebG, aG); WLOAD(wdG, (unsigned long long)(wordsp + t0 + 16 * tdir));
    GLOAD2(ebH, aH); WLOAD(wdH, (unsigned long long)(wordsp + t0 + 17 * tdir));
    GLOAD2(ebI, aJ); WLOAD(wdI, (unsigned long long)(wordsp + t0 + 18 * tdir));

    SWAIT(27);                                   // ei (oldest 2) complete

    // X init = g o e_{t0}   (entry kc at ei[kc>>1], words (kc&1)*2, +1)
    bf16x4 X[4];
#pragma unroll
    for (int kc = 0; kc < 4; ++kc) {
        unsigned ex = ei[kc >> 1][(kc & 1) * 2];
        unsigned ey = ei[kc >> 1][(kc & 1) * 2 + 1];
        float f0 = __uint_as_float(ex << 16)         * g[kc][0];
        float f1 = __uint_as_float(ex & 0xffff0000u) * g[kc][1];
        float f2 = __uint_as_float(ey << 16)         * g[kc][2];
        float f3 = __uint_as_float(ey & 0xffff0000u) * g[kc][3];
        X[kc] = pack4(f0, f1, f2, f3);
    }

    float xf[4][4];                              // last step's f32 products

    // substep for step s: MFMA (regs only) BEFORE the wait; then drain the
    // 9-back group (this step's emission + this refill's word), consume,
    // refill emission for s+9, fetch word for s+18. Exactly 3 asm VMEM.
    auto substep = [&](u32x4 (&eb)[2], int& wd, int widx) {
        f32x4 D[4];
#pragma unroll
        for (int mt = 0; mt < 4; ++mt) { f32x4 z = {0.f, 0.f, 0.f, 0.f}; D[mt] = z; }
#pragma unroll
        for (int kc = 0; kc < 4; ++kc)
#pragma unroll
            for (int mt = 0; mt < 4; ++mt)
                D[mt] = __builtin_amdgcn_mfma_f32_16x16x16bf16_1k(Sf[mt][kc], X[kc], D[mt], 0, 0, 0);
        SWAIT(24);                               // 9-back group (2G+1W) done
#pragma unroll
        for (int kc = 0; kc < 4; ++kc) {
            unsigned ex = eb[kc >> 1][(kc & 1) * 2];
            unsigned ey = eb[kc >> 1][(kc & 1) * 2 + 1];
            float f0 = __uint_as_float(ex << 16);
            float f1 = __uint_as_float(ex & 0xffff0000u);
            float f2 = __uint_as_float(ey << 16);
            float f3 = __uint_as_float(ey & 0xffff0000u);
            xf[kc][0] = D[kc][0] * f0;  xf[kc][1] = D[kc][1] * f1;
            xf[kc][2] = D[kc][2] * f2;  xf[kc][3] = D[kc][3] * f3;
            X[kc] = pack4(xf[kc][0], xf[kc][1], xf[kc][2], xf[kc][3]);
        }
        unsigned long long a = btbp + (unsigned long long)wd * 128u;
        GLOAD2(eb, a);
        WLOAD(wd, (unsigned long long)(wordsp + widx));
    };

    // 126 steps = 14 x 9; word index bounds: fwd max 1+144=145<256,
    // bwd min 254-144=110>=0.
    for (int i = 0; i < 126; i += 9) {
        substep(ebA, wdA, t0 + tdir * (i + 19));
        substep(ebB, wdB, t0 + tdir * (i + 20));
        substep(ebC, wdC, t0 + tdir * (i + 21));
        substep(ebD, wdD, t0 + tdir * (i + 22));
        substep(ebE, wdE, t0 + tdir * (i + 23));
        substep(ebF, wdF, t0 + tdir * (i + 24));
        substep(ebG, wdG, t0 + tdir * (i + 25));
        substep(ebH, wdH, t0 + tdir * (i + 26));
        substep(ebI, wdI, t0 + tdir * (i + 27));
    }

    if (wv == 0) {
        // extra step: Y = S^T alpha_127 (no emission) -> LDS
        f32x4 D[4];
#pragma unroll
        for (int mt = 0; mt < 4; ++mt) { f32x4 z = {0.f, 0.f, 0.f, 0.f}; D[mt] = z; }
#pragma unroll
        for (int kc = 0; kc < 4; ++kc)
#pragma unroll
            for (int mt = 0; mt < 4; ++mt)
                D[mt] = __builtin_amdgcn_mfma_f32_16x16x16bf16_1k(Sf[mt][kc], X[kc], D[mt], 0, 0, 0);
#pragma unroll
        for (int mt = 0; mt < 4; ++mt) {
            float4 o = {D[mt][0], D[mt][1], D[mt][2], D[mt][3]};
            *(float4*)&ytile[l * 68 + mt * 16 + q * 4] = o;
        }
    }
    __syncthreads();
    if (wv == 1) {
        // z[s] = sum_tag Y[tag][s] * X128[tag][s]
        float p = 0.f;
#pragma unroll
        for (int mt = 0; mt < 4; ++mt)
#pragma unroll
            for (int r = 0; r < 4; ++r)
                p = fmaf(ytile[l * 68 + mt * 16 + q * 4 + r], xf[mt][r], p);
        p += __shfl_xor(p, 16, 64);
        p += __shfl_xor(p, 32, 64);
        if (lane < 16)
            out[sbase + l] = logf(p) + 255.0f * LOG64;
    }
}

extern "C" void kernel_launch(void* const* d_in, const int* in_sizes, int n_in,
                              void* d_out, int out_size, void* d_ws, size_t ws_size,
                              hipStream_t stream) {
    const int*   words  = (const int*)d_in[0];
    const float* ThetaB = (const float*)d_in[1];
    const float* WA     = (const float*)d_in[2];
    const float* E      = (const float*)d_in[3];
    float*       outp   = (float*)d_out;
    uint2*       Btb    = (uint2*)d_ws;          // 50002*128 B = 6.4 MB

    // 782 blocks x 1 wave x 4 word-tiles = 50048 >= 50002 rows
    emis_mfma<<<dim3(782), dim3(64), 0, stream>>>(ThetaB, E, Btb);
    // 128 blocks x (fwd wave + bwd wave), 16 sentences each
    crf_fwdbwd<<<dim3(128), dim3(128), 0, stream>>>(words, WA, Btb, outp);
}